// Round 1
// baseline (527.732 us; speedup 1.0000x reference)
//
#include <hip/hip_runtime.h>
#include <hip/hip_bf16.h>
#include <math.h>

#define N_NODES 40000
#define N_EDGES 320000
#define F_IN 128
#define NHEAD 4
#define CH 64
#define HC 256
#define NOUT 64

// ---------------- CSR build ----------------
__global__ __launch_bounds__(256) void hist_kernel(const int* __restrict__ ei,
                                                   int* __restrict__ deg) {
    int e = blockIdx.x * 256 + threadIdx.x;
    if (e < N_EDGES) atomicAdd(&deg[ei[N_EDGES + e]], 1);
}

__global__ __launch_bounds__(1024) void scan_kernel(const int* __restrict__ deg,
                                                    int* __restrict__ rowstart) {
    __shared__ int sm[1024];
    __shared__ int carry_s;
    int t = threadIdx.x;
    if (t == 0) carry_s = 0;
    __syncthreads();
    for (int c0 = 0; c0 < N_NODES; c0 += 1024) {
        int i = c0 + t;
        int v = (i < N_NODES) ? deg[i] : 0;
        sm[t] = v;
        __syncthreads();
        for (int off = 1; off < 1024; off <<= 1) {
            int x = (t >= off) ? sm[t - off] : 0;
            __syncthreads();
            sm[t] += x;
            __syncthreads();
        }
        int incl = sm[t];
        int carry = carry_s;
        if (i < N_NODES) rowstart[i] = carry + incl - v;
        __syncthreads();
        if (t == 1023) carry_s = carry + sm[1023];
        __syncthreads();
    }
    if (t == 0) rowstart[N_NODES] = carry_s;
}

__global__ __launch_bounds__(256) void scatter_kernel(const int* __restrict__ ei,
                                                      const int* __restrict__ rowstart,
                                                      int* __restrict__ cursor,
                                                      int* __restrict__ esorted) {
    int e = blockIdx.x * 256 + threadIdx.x;
    if (e >= N_EDGES) return;
    int d = ei[N_EDGES + e];
    int s = ei[e];
    int pos = rowstart[d] + atomicAdd(&cursor[d], 1);
    esorted[pos] = s;
}

// ---------------- f32 tiled GEMM: C[M,Nc] = A[M,K] @ B[K,Nc] ----------------
__global__ __launch_bounds__(256) void gemm_f32(const float* __restrict__ A,
                                                const float* __restrict__ B,
                                                float* __restrict__ C,
                                                int K, int Nc) {
    __shared__ float As[32][68];
    __shared__ float Bs[32][68];
    int tid = threadIdx.x;
    int tx = tid & 15, ty = tid >> 4;
    int row0 = blockIdx.x * 64, col0 = blockIdx.y * 64;
    float acc[4][4] = {};
    for (int k0 = 0; k0 < K; k0 += 32) {
        int a_k = (tid & 7) * 4, a_m = tid >> 3;
#pragma unroll
        for (int p = 0; p < 2; ++p) {
            int m = a_m + p * 32;
            float4 v = *(const float4*)(A + (size_t)(row0 + m) * K + k0 + a_k);
            As[a_k + 0][m] = v.x; As[a_k + 1][m] = v.y;
            As[a_k + 2][m] = v.z; As[a_k + 3][m] = v.w;
        }
        int b_n = (tid & 15) * 4, b_k = tid >> 4;
#pragma unroll
        for (int p = 0; p < 2; ++p) {
            int kk = b_k + p * 16;
            float4 v = *(const float4*)(B + (size_t)(k0 + kk) * Nc + col0 + b_n);
            Bs[kk][b_n + 0] = v.x; Bs[kk][b_n + 1] = v.y;
            Bs[kk][b_n + 2] = v.z; Bs[kk][b_n + 3] = v.w;
        }
        __syncthreads();
#pragma unroll
        for (int kk = 0; kk < 32; ++kk) {
            float a[4], b[4];
#pragma unroll
            for (int i = 0; i < 4; ++i) a[i] = As[kk][ty * 4 + i];
#pragma unroll
            for (int j = 0; j < 4; ++j) b[j] = Bs[kk][tx * 4 + j];
#pragma unroll
            for (int i = 0; i < 4; ++i)
#pragma unroll
                for (int j = 0; j < 4; ++j) acc[i][j] += a[i] * b[j];
        }
        __syncthreads();
    }
#pragma unroll
    for (int i = 0; i < 4; ++i) {
        int r = row0 + ty * 4 + i;
        float4 v = make_float4(acc[i][0], acc[i][1], acc[i][2], acc[i][3]);
        *(float4*)(C + (size_t)r * Nc + col0 + tx * 4) = v;
    }
}

// ---------------- attention scores per node ----------------
// e_src[n][h] = dot(h[n, h*64:...], a_src[h]); same for dst. 4 nodes/block.
__global__ __launch_bounds__(256) void scores_kernel(const float* __restrict__ h,
                                                     const float* __restrict__ a_src,
                                                     const float* __restrict__ a_dst,
                                                     float* __restrict__ es,
                                                     float* __restrict__ ed) {
    int node = blockIdx.x * 4 + (threadIdx.x >> 6);
    int lane = threadIdx.x & 63;
    int hh = lane >> 4;
    float4 hv = *(const float4*)(h + (size_t)node * HC + lane * 4);
    float4 as = *(const float4*)(a_src + lane * 4);
    float4 ad = *(const float4*)(a_dst + lane * 4);
    float ps = hv.x * as.x + hv.y * as.y + hv.z * as.z + hv.w * as.w;
    float pd = hv.x * ad.x + hv.y * ad.y + hv.z * ad.z + hv.w * ad.w;
#pragma unroll
    for (int off = 1; off < 16; off <<= 1) {
        ps += __shfl_xor(ps, off, 16);
        pd += __shfl_xor(pd, off, 16);
    }
    if ((lane & 15) == 0) {
        es[node * NHEAD + hh] = ps;
        ed[node * NHEAD + hh] = pd;
    }
}

// ---------------- per-dst softmax + weighted aggregation ----------------
// one wave per node; lane l handles channels l*4..l*4+3 (head = l>>4)
__global__ __launch_bounds__(256) void aggregate_kernel(const float* __restrict__ h,
                                                        const float* __restrict__ es,
                                                        const float* __restrict__ ed,
                                                        const int* __restrict__ rowstart,
                                                        const int* __restrict__ esorted,
                                                        const float* __restrict__ bias,
                                                        float* __restrict__ out) {
    int node = blockIdx.x * 4 + (threadIdx.x >> 6);
    int lane = threadIdx.x & 63;
    int hh = lane >> 4;
    float edv = ed[node * NHEAD + hh];
    int beg = rowstart[node], end = rowstart[node + 1];
    float dloc = 0.f;
    for (int i = beg; i < end; ++i) {
        int s = esorted[i];
        float e = es[s * NHEAD + hh] + edv;
        e = e > 0.f ? e : 0.2f * e;
        dloc += expf(e);
    }
    float inv = 1.f / (dloc + 1e-16f);
    float4 acc = make_float4(0.f, 0.f, 0.f, 0.f);
    for (int i = beg; i < end; ++i) {
        int s = esorted[i];
        float e = es[s * NHEAD + hh] + edv;
        e = e > 0.f ? e : 0.2f * e;
        float alpha = expf(e) * inv;
        float4 hv = *(const float4*)(h + (size_t)s * HC + lane * 4);
        acc.x += alpha * hv.x; acc.y += alpha * hv.y;
        acc.z += alpha * hv.z; acc.w += alpha * hv.w;
    }
    float4 bv = *(const float4*)(bias + lane * 4);
    acc.x += bv.x; acc.y += bv.y; acc.z += bv.z; acc.w += bv.w;
    *(float4*)(out + (size_t)node * HC + lane * 4) = acc;
}

// ---------------- batch norm ----------------
__global__ __launch_bounds__(256) void bn_stats_kernel(const float* __restrict__ x,
                                                       float* __restrict__ acc) {
    int c = threadIdx.x;
    int r0 = blockIdx.x * 200;
    float s = 0.f, s2 = 0.f;
    for (int r = r0; r < r0 + 200; ++r) {
        float v = x[(size_t)r * HC + c];
        s += v; s2 += v * v;
    }
    atomicAdd(&acc[c], s);
    atomicAdd(&acc[HC + c], s2);
}

__global__ __launch_bounds__(256) void bn_finalize_kernel(const float* __restrict__ acc,
                                                          const float* __restrict__ gamma,
                                                          const float* __restrict__ beta,
                                                          float* __restrict__ sc) {
    int c = threadIdx.x;
    float mean = acc[c] * (1.f / N_NODES);
    float var = acc[HC + c] * (1.f / N_NODES) - mean * mean;
    float inv = rsqrtf(var + 1e-5f);
    float scale = gamma[c] * inv;
    sc[c] = scale;
    sc[HC + c] = beta[c] - mean * scale;
}

// in-place: x = elu(x*scale + shift)
__global__ __launch_bounds__(256) void bn_apply_elu_kernel(float* __restrict__ x,
                                                           const float* __restrict__ sc) {
    int idx = blockIdx.x * 256 + threadIdx.x;
    size_t off = (size_t)idx * 4;
    int c = (int)(off & (HC - 1));
    float4 v = *(float4*)(x + off);
    v.x = v.x * sc[c + 0] + sc[HC + c + 0];
    v.y = v.y * sc[c + 1] + sc[HC + c + 1];
    v.z = v.z * sc[c + 2] + sc[HC + c + 2];
    v.w = v.w * sc[c + 3] + sc[HC + c + 3];
    v.x = v.x > 0.f ? v.x : expm1f(v.x);
    v.y = v.y > 0.f ? v.y : expm1f(v.y);
    v.z = v.z > 0.f ? v.z : expm1f(v.z);
    v.w = v.w > 0.f ? v.w : expm1f(v.w);
    *(float4*)(x + off) = v;
}

// ---------------- final: out = max(h1,h2) @ linW + linb ----------------
__global__ __launch_bounds__(256) void final_gemm_kernel(const float* __restrict__ A1,
                                                         const float* __restrict__ A2,
                                                         const float* __restrict__ B,
                                                         const float* __restrict__ bias,
                                                         float* __restrict__ C) {
    __shared__ float As[32][68];
    __shared__ float Bs[32][68];
    int tid = threadIdx.x;
    int tx = tid & 15, ty = tid >> 4;
    int row0 = blockIdx.x * 64;
    float acc[4][4] = {};
    for (int k0 = 0; k0 < HC; k0 += 32) {
        int a_k = (tid & 7) * 4, a_m = tid >> 3;
#pragma unroll
        for (int p = 0; p < 2; ++p) {
            int m = a_m + p * 32;
            size_t base = (size_t)(row0 + m) * HC + k0 + a_k;
            float4 v1 = *(const float4*)(A1 + base);
            float4 v2 = *(const float4*)(A2 + base);
            As[a_k + 0][m] = fmaxf(v1.x, v2.x);
            As[a_k + 1][m] = fmaxf(v1.y, v2.y);
            As[a_k + 2][m] = fmaxf(v1.z, v2.z);
            As[a_k + 3][m] = fmaxf(v1.w, v2.w);
        }
        int b_n = (tid & 15) * 4, b_k = tid >> 4;
#pragma unroll
        for (int p = 0; p < 2; ++p) {
            int kk = b_k + p * 16;
            float4 v = *(const float4*)(B + (size_t)(k0 + kk) * NOUT + b_n);
            Bs[kk][b_n + 0] = v.x; Bs[kk][b_n + 1] = v.y;
            Bs[kk][b_n + 2] = v.z; Bs[kk][b_n + 3] = v.w;
        }
        __syncthreads();
#pragma unroll
        for (int kk = 0; kk < 32; ++kk) {
            float a[4], b[4];
#pragma unroll
            for (int i = 0; i < 4; ++i) a[i] = As[kk][ty * 4 + i];
#pragma unroll
            for (int j = 0; j < 4; ++j) b[j] = Bs[kk][tx * 4 + j];
#pragma unroll
            for (int i = 0; i < 4; ++i)
#pragma unroll
                for (int j = 0; j < 4; ++j) acc[i][j] += a[i] * b[j];
        }
        __syncthreads();
    }
#pragma unroll
    for (int i = 0; i < 4; ++i) {
        int r = row0 + ty * 4 + i;
#pragma unroll
        for (int j = 0; j < 4; ++j)
            C[(size_t)r * NOUT + tx * 4 + j] = acc[i][j] + bias[tx * 4 + j];
    }
}

extern "C" void kernel_launch(void* const* d_in, const int* in_sizes, int n_in,
                              void* d_out, int out_size, void* d_ws, size_t ws_size,
                              hipStream_t stream) {
    const float* x       = (const float*)d_in[0];
    const int*   ei      = (const int*)d_in[1];
    const float* W1      = (const float*)d_in[2];
    const float* a1_src  = (const float*)d_in[3];
    const float* a1_dst  = (const float*)d_in[4];
    const float* b1      = (const float*)d_in[5];
    const float* bn_g    = (const float*)d_in[6];
    const float* bn_b    = (const float*)d_in[7];
    const float* W2      = (const float*)d_in[8];
    const float* a2_src  = (const float*)d_in[9];
    const float* a2_dst  = (const float*)d_in[10];
    const float* b2      = (const float*)d_in[11];
    const float* linW    = (const float*)d_in[12];
    const float* linb    = (const float*)d_in[13];
    float* out = (float*)d_out;

    char* ws = (char*)d_ws;
    const size_t NHC_B = (size_t)N_NODES * HC * 4;  // 40,960,000
    float* buf_h   = (float*)(ws);                       // h_pre (both layers)
    float* buf_t   = (float*)(ws + NHC_B);               // agg1 -> h1
    float* buf_o   = (float*)(ws + 2 * NHC_B);           // agg2 (h2)
    char*  p       = ws + 3 * NHC_B;
    float* e_src   = (float*)p;  p += (size_t)N_NODES * NHEAD * 4;
    float* e_dst   = (float*)p;  p += (size_t)N_NODES * NHEAD * 4;
    int*   deg     = (int*)p;    p += (size_t)N_NODES * 4;
    int*   cursor  = (int*)p;    p += (size_t)N_NODES * 4;
    int*   rowstart= (int*)p;    p += ((size_t)N_NODES + 64) * 4;
    int*   esorted = (int*)p;    p += (size_t)N_EDGES * 4;
    float* bnacc   = (float*)p;  p += 2 * HC * 4;
    float* bnsc    = (float*)p;  p += 2 * HC * 4;

    // zero: deg + cursor (adjacent), bn accumulators
    hipMemsetAsync(deg, 0, (size_t)N_NODES * 2 * 4, stream);
    hipMemsetAsync(bnacc, 0, 2 * HC * 4, stream);

    // CSR build (graph is identical for both layers)
    hist_kernel<<<(N_EDGES + 255) / 256, 256, 0, stream>>>(ei, deg);
    scan_kernel<<<1, 1024, 0, stream>>>(deg, rowstart);
    scatter_kernel<<<(N_EDGES + 255) / 256, 256, 0, stream>>>(ei, rowstart, cursor, esorted);

    // ---- layer 1 ----
    gemm_f32<<<dim3(N_NODES / 64, HC / 64), 256, 0, stream>>>(x, W1, buf_h, F_IN, HC);
    scores_kernel<<<N_NODES / 4, 256, 0, stream>>>(buf_h, a1_src, a1_dst, e_src, e_dst);
    aggregate_kernel<<<N_NODES / 4, 256, 0, stream>>>(buf_h, e_src, e_dst, rowstart,
                                                      esorted, b1, buf_t);
    bn_stats_kernel<<<N_NODES / 200, 256, 0, stream>>>(buf_t, bnacc);
    bn_finalize_kernel<<<1, 256, 0, stream>>>(bnacc, bn_g, bn_b, bnsc);
    bn_apply_elu_kernel<<<(N_NODES * HC / 4) / 256, 256, 0, stream>>>(buf_t, bnsc);

    // ---- layer 2 ----
    gemm_f32<<<dim3(N_NODES / 64, HC / 64), 256, 0, stream>>>(buf_t, W2, buf_h, HC, HC);
    scores_kernel<<<N_NODES / 4, 256, 0, stream>>>(buf_h, a2_src, a2_dst, e_src, e_dst);
    aggregate_kernel<<<N_NODES / 4, 256, 0, stream>>>(buf_h, e_src, e_dst, rowstart,
                                                      esorted, b2, buf_o);

    // ---- JK max + final linear ----
    final_gemm_kernel<<<N_NODES / 64, 256, 0, stream>>>(buf_t, buf_o, linW, linb, out);
}

// Round 2
// 325.025 us; speedup vs baseline: 1.6237x; 1.6237x over previous
//
#include <hip/hip_runtime.h>
#include <math.h>

#define N_NODES 40000
#define N_EDGES 320000
#define F_IN 128
#define NHEAD 4
#define HC 256
#define NOUT 64

typedef __attribute__((ext_vector_type(8))) __bf16 bf16x8;
typedef __attribute__((ext_vector_type(4))) float f32x4;

static __device__ __forceinline__ unsigned short f2bf(float f) {
    union { float f; unsigned u; } v; v.f = f;
    unsigned r = v.u + 0x7FFFu + ((v.u >> 16) & 1u);
    return (unsigned short)(r >> 16);
}
static __device__ __forceinline__ float bf2f(unsigned short s) {
    union { unsigned u; float f; } v; v.u = ((unsigned)s) << 16;
    return v.f;
}

// ---------------- CSR build ----------------
__global__ __launch_bounds__(256) void hist_kernel(const int* __restrict__ ei,
                                                   int* __restrict__ deg) {
    int e = blockIdx.x * 256 + threadIdx.x;
    if (e < N_EDGES) atomicAdd(&deg[ei[N_EDGES + e]], 1);
}

// phase A: per-block (1024 nodes) exclusive scan, write local-excl + block sum
__global__ __launch_bounds__(1024) void scanA_kernel(const int* __restrict__ deg,
                                                     int* __restrict__ rowstart,
                                                     int* __restrict__ blocksum) {
    __shared__ int sm[1024];
    int t = threadIdx.x;
    int i = blockIdx.x * 1024 + t;
    int v = (i < N_NODES) ? deg[i] : 0;
    sm[t] = v;
    __syncthreads();
    for (int off = 1; off < 1024; off <<= 1) {
        int x = (t >= off) ? sm[t - off] : 0;
        __syncthreads();
        sm[t] += x;
        __syncthreads();
    }
    if (i < N_NODES) rowstart[i] = sm[t] - v;
    if (t == 1023) blocksum[blockIdx.x] = sm[1023];
}

// phase B: scan the 40 block sums (single wave)
__global__ __launch_bounds__(64) void scanB_kernel(int* __restrict__ blocksum,
                                                   int* __restrict__ blockoff) {
    int t = threadIdx.x;
    int v = (t < 40) ? blocksum[t] : 0;
    int s = v;
#pragma unroll
    for (int off = 1; off < 64; off <<= 1) {
        int x = __shfl_up(s, off, 64);
        if (t >= off) s += x;
    }
    if (t < 40) blockoff[t] = s - v;
}

// phase C: add block offsets; set rowstart[N]
__global__ __launch_bounds__(1024) void scanC_kernel(int* __restrict__ rowstart,
                                                     const int* __restrict__ blockoff) {
    int i = blockIdx.x * 1024 + threadIdx.x;
    if (i < N_NODES) rowstart[i] += blockoff[blockIdx.x];
    if (i == 0) rowstart[N_NODES] = N_EDGES;
}

__global__ __launch_bounds__(256) void scatter_kernel(const int* __restrict__ ei,
                                                      const int* __restrict__ rowstart,
                                                      int* __restrict__ cursor,
                                                      int* __restrict__ esorted) {
    int e = blockIdx.x * 256 + threadIdx.x;
    if (e >= N_EDGES) return;
    int d = ei[N_EDGES + e];
    int s = ei[e];
    int pos = rowstart[d] + atomicAdd(&cursor[d], 1);
    esorted[pos] = s;
}

// ---------------- converts ----------------
__global__ __launch_bounds__(256) void cvt_f32_bf16_kernel(const float* __restrict__ x,
                                                           unsigned short* __restrict__ y,
                                                           int n4) {
    int i = blockIdx.x * 256 + threadIdx.x;
    if (i >= n4) return;
    float4 v = *(const float4*)(x + (size_t)i * 4);
    ushort4 o;
    o.x = f2bf(v.x); o.y = f2bf(v.y); o.z = f2bf(v.z); o.w = f2bf(v.w);
    *(ushort4*)(y + (size_t)i * 4) = o;
}

// W [K,N] f32 -> Wt [N,K] bf16
__global__ __launch_bounds__(256) void wconv_kernel(const float* __restrict__ W,
                                                    unsigned short* __restrict__ Wt,
                                                    int K, int Nc) {
    int t = blockIdx.x * 256 + threadIdx.x;
    if (t >= K * Nc) return;
    int k = t / Nc, n = t - k * Nc;
    Wt[(size_t)n * K + k] = f2bf(W[t]);
}

// ---------------- MFMA bf16 GEMM, 64x64 tile, 256 threads ----------------
// MODE 0: C_bf16[M,Nc] = A_bf16[M,K] @ Bt[Nc,K]^T
// MODE 1: C_f32[M,Nc]  = bf16(max(A1f,A2f)) @ Bt^T + bias
template <int MODE>
__global__ __launch_bounds__(256) void mfma_gemm(const unsigned short* __restrict__ A,
                                                 const float* __restrict__ A1f,
                                                 const float* __restrict__ A2f,
                                                 const unsigned short* __restrict__ Bt,
                                                 unsigned short* __restrict__ Cb,
                                                 float* __restrict__ Cf,
                                                 const float* __restrict__ bias,
                                                 int K, int Nc) {
    __shared__ unsigned short As[64 * 32];
    __shared__ unsigned short Bs[64 * 32];
    int tid = threadIdx.x;
    int row0 = blockIdx.x * 64, col0 = blockIdx.y * 64;
    int wave = tid >> 6, lane = tid & 63;
    int wm = wave >> 1, wn = wave & 1;
    int quad = lane >> 4, l16 = lane & 15;
    f32x4 acc[2][2];
#pragma unroll
    for (int mi = 0; mi < 2; ++mi)
#pragma unroll
        for (int ni = 0; ni < 2; ++ni) acc[mi][ni] = (f32x4){0.f, 0.f, 0.f, 0.f};

    int srow = tid >> 2, schunk = (tid & 3) * 8;
    for (int kc = 0; kc < K; kc += 32) {
        if (MODE == 0) {
            int4 av = *(const int4*)(A + (size_t)(row0 + srow) * K + kc + schunk);
            *(int4*)(&As[srow * 32 + schunk]) = av;
        } else {
            size_t base = (size_t)(row0 + srow) * K + kc + schunk;
            float4 u1 = *(const float4*)(A1f + base);
            float4 u2 = *(const float4*)(A1f + base + 4);
            float4 v1 = *(const float4*)(A2f + base);
            float4 v2 = *(const float4*)(A2f + base + 4);
            ushort4 o1, o2;
            o1.x = f2bf(fmaxf(u1.x, v1.x)); o1.y = f2bf(fmaxf(u1.y, v1.y));
            o1.z = f2bf(fmaxf(u1.z, v1.z)); o1.w = f2bf(fmaxf(u1.w, v1.w));
            o2.x = f2bf(fmaxf(u2.x, v2.x)); o2.y = f2bf(fmaxf(u2.y, v2.y));
            o2.z = f2bf(fmaxf(u2.z, v2.z)); o2.w = f2bf(fmaxf(u2.w, v2.w));
            *(ushort4*)(&As[srow * 32 + schunk]) = o1;
            *(ushort4*)(&As[srow * 32 + schunk + 4]) = o2;
        }
        {
            int4 bv = *(const int4*)(Bt + (size_t)(col0 + srow) * K + kc + schunk);
            *(int4*)(&Bs[srow * 32 + schunk]) = bv;
        }
        __syncthreads();
        bf16x8 af[2], bfr[2];
#pragma unroll
        for (int mi = 0; mi < 2; ++mi)
            af[mi] = *(const bf16x8*)(&As[(wm * 32 + mi * 16 + l16) * 32 + quad * 8]);
#pragma unroll
        for (int ni = 0; ni < 2; ++ni)
            bfr[ni] = *(const bf16x8*)(&Bs[(wn * 32 + ni * 16 + l16) * 32 + quad * 8]);
#pragma unroll
        for (int mi = 0; mi < 2; ++mi)
#pragma unroll
            for (int ni = 0; ni < 2; ++ni)
                acc[mi][ni] = __builtin_amdgcn_mfma_f32_16x16x32_bf16(
                    af[mi], bfr[ni], acc[mi][ni], 0, 0, 0);
        __syncthreads();
    }
#pragma unroll
    for (int mi = 0; mi < 2; ++mi)
#pragma unroll
        for (int ni = 0; ni < 2; ++ni) {
            int r0 = row0 + wm * 32 + mi * 16 + quad * 4;
            int c = col0 + wn * 32 + ni * 16 + l16;
#pragma unroll
            for (int r = 0; r < 4; ++r) {
                if (MODE == 0)
                    Cb[(size_t)(r0 + r) * Nc + c] = f2bf(acc[mi][ni][r]);
                else
                    Cf[(size_t)(r0 + r) * Nc + c] = acc[mi][ni][r] + bias[c];
            }
        }
}

// ---------------- attention scores per node (bf16 h) ----------------
__global__ __launch_bounds__(256) void scores_kernel(const unsigned short* __restrict__ h,
                                                     const float* __restrict__ a_src,
                                                     const float* __restrict__ a_dst,
                                                     float* __restrict__ es,
                                                     float* __restrict__ ed) {
    int node = blockIdx.x * 4 + (threadIdx.x >> 6);
    int lane = threadIdx.x & 63;
    int hh = lane >> 4;
    ushort4 hv = *(const ushort4*)(h + (size_t)node * HC + lane * 4);
    float4 as = *(const float4*)(a_src + lane * 4);
    float4 ad = *(const float4*)(a_dst + lane * 4);
    float h0 = bf2f(hv.x), h1 = bf2f(hv.y), h2 = bf2f(hv.z), h3 = bf2f(hv.w);
    float ps = h0 * as.x + h1 * as.y + h2 * as.z + h3 * as.w;
    float pd = h0 * ad.x + h1 * ad.y + h2 * ad.z + h3 * ad.w;
#pragma unroll
    for (int off = 1; off < 16; off <<= 1) {
        ps += __shfl_xor(ps, off, 16);
        pd += __shfl_xor(pd, off, 16);
    }
    if ((lane & 15) == 0) {
        es[node * NHEAD + hh] = ps;
        ed[node * NHEAD + hh] = pd;
    }
}

// ---------------- single-pass softmax + aggregation (bf16 gather) -----------
__global__ __launch_bounds__(256) void aggregate_kernel(const unsigned short* __restrict__ h,
                                                        const float* __restrict__ es,
                                                        const float* __restrict__ ed,
                                                        const int* __restrict__ rowstart,
                                                        const int* __restrict__ esorted,
                                                        const float* __restrict__ bias,
                                                        float* __restrict__ out) {
    int node = blockIdx.x * 4 + (threadIdx.x >> 6);
    int lane = threadIdx.x & 63;
    int hh = lane >> 4;
    float edv = ed[node * NHEAD + hh];
    int beg = rowstart[node], end = rowstart[node + 1];
    float dsum = 0.f;
    float4 acc = make_float4(0.f, 0.f, 0.f, 0.f);
    for (int i = beg; i < end; ++i) {
        int s = esorted[i];
        float e = es[s * NHEAD + hh] + edv;
        e = e > 0.f ? e : 0.2f * e;
        float w = __expf(e);
        dsum += w;
        ushort4 hv = *(const ushort4*)(h + (size_t)s * HC + lane * 4);
        acc.x += w * bf2f(hv.x);
        acc.y += w * bf2f(hv.y);
        acc.z += w * bf2f(hv.z);
        acc.w += w * bf2f(hv.w);
    }
    float inv = 1.f / (dsum + 1e-16f);
    float4 bv = *(const float4*)(bias + lane * 4);
    float4 o;
    o.x = acc.x * inv + bv.x;
    o.y = acc.y * inv + bv.y;
    o.z = acc.z * inv + bv.z;
    o.w = acc.w * inv + bv.w;
    *(float4*)(out + (size_t)node * HC + lane * 4) = o;
}

// ---------------- batch norm ----------------
__global__ __launch_bounds__(256) void bn_stats_kernel(const float* __restrict__ x,
                                                       float* __restrict__ acc) {
    int c = threadIdx.x;
    int r0 = blockIdx.x * 200;
    float s = 0.f, s2 = 0.f;
    for (int r = r0; r < r0 + 200; ++r) {
        float v = x[(size_t)r * HC + c];
        s += v; s2 += v * v;
    }
    atomicAdd(&acc[c], s);
    atomicAdd(&acc[HC + c], s2);
}

__global__ __launch_bounds__(256) void bn_finalize_kernel(const float* __restrict__ acc,
                                                          const float* __restrict__ gamma,
                                                          const float* __restrict__ beta,
                                                          float* __restrict__ sc) {
    int c = threadIdx.x;
    float mean = acc[c] * (1.f / N_NODES);
    float var = acc[HC + c] * (1.f / N_NODES) - mean * mean;
    float inv = rsqrtf(var + 1e-5f);
    float scale = gamma[c] * inv;
    sc[c] = scale;
    sc[HC + c] = beta[c] - mean * scale;
}

// x = elu(x*scale+shift) in-place (f32) + bf16 copy
__global__ __launch_bounds__(256) void bn_apply_elu_kernel(float* __restrict__ x,
                                                           unsigned short* __restrict__ xb,
                                                           const float* __restrict__ sc) {
    int idx = blockIdx.x * 256 + threadIdx.x;
    size_t off = (size_t)idx * 4;
    int c = (int)(off & (HC - 1));
    float4 v = *(float4*)(x + off);
    v.x = v.x * sc[c + 0] + sc[HC + c + 0];
    v.y = v.y * sc[c + 1] + sc[HC + c + 1];
    v.z = v.z * sc[c + 2] + sc[HC + c + 2];
    v.w = v.w * sc[c + 3] + sc[HC + c + 3];
    v.x = v.x > 0.f ? v.x : expm1f(v.x);
    v.y = v.y > 0.f ? v.y : expm1f(v.y);
    v.z = v.z > 0.f ? v.z : expm1f(v.z);
    v.w = v.w > 0.f ? v.w : expm1f(v.w);
    *(float4*)(x + off) = v;
    ushort4 o;
    o.x = f2bf(v.x); o.y = f2bf(v.y); o.z = f2bf(v.z); o.w = f2bf(v.w);
    *(ushort4*)(xb + off) = o;
}

extern "C" void kernel_launch(void* const* d_in, const int* in_sizes, int n_in,
                              void* d_out, int out_size, void* d_ws, size_t ws_size,
                              hipStream_t stream) {
    const float* x      = (const float*)d_in[0];
    const int*   ei     = (const int*)d_in[1];
    const float* W1     = (const float*)d_in[2];
    const float* a1_src = (const float*)d_in[3];
    const float* a1_dst = (const float*)d_in[4];
    const float* b1     = (const float*)d_in[5];
    const float* bn_g   = (const float*)d_in[6];
    const float* bn_b   = (const float*)d_in[7];
    const float* W2     = (const float*)d_in[8];
    const float* a2_src = (const float*)d_in[9];
    const float* a2_dst = (const float*)d_in[10];
    const float* b2     = (const float*)d_in[11];
    const float* linW   = (const float*)d_in[12];
    const float* linb   = (const float*)d_in[13];
    float* out = (float*)d_out;

    char* ws = (char*)d_ws;
    const size_t NHC_F32 = (size_t)N_NODES * HC * 4;   // 40.96 MB
    const size_t NHC_BF  = (size_t)N_NODES * HC * 2;   // 20.48 MB
    float*          h1      = (float*)(ws);                 // agg1 out -> h1 (f32)
    float*          h2      = (float*)(ws + NHC_F32);       // agg2 out (f32)
    unsigned short* hpre_b  = (unsigned short*)(ws + 2 * NHC_F32);
    unsigned short* h1_b    = (unsigned short*)(ws + 2 * NHC_F32 + NHC_BF);
    char* p = ws + 2 * NHC_F32 + 2 * NHC_BF;
    unsigned short* x_b     = (unsigned short*)p; p += (size_t)N_NODES * F_IN * 2;
    unsigned short* W1t     = (unsigned short*)p; p += (size_t)F_IN * HC * 2;
    unsigned short* W2t     = (unsigned short*)p; p += (size_t)HC * HC * 2;
    unsigned short* linWt   = (unsigned short*)p; p += (size_t)HC * NOUT * 2;
    float* e_src   = (float*)p;  p += (size_t)N_NODES * NHEAD * 4;
    float* e_dst   = (float*)p;  p += (size_t)N_NODES * NHEAD * 4;
    int*   deg     = (int*)p;    p += (size_t)N_NODES * 4;
    int*   cursor  = (int*)p;    p += (size_t)N_NODES * 4;
    int*   rowstart= (int*)p;    p += ((size_t)N_NODES + 64) * 4;
    int*   esorted = (int*)p;    p += (size_t)N_EDGES * 4;
    int*   blocksum= (int*)p;    p += 64 * 4;
    int*   blockoff= (int*)p;    p += 64 * 4;
    float* bnacc   = (float*)p;  p += 2 * HC * 4;
    float* bnsc    = (float*)p;  p += 2 * HC * 4;

    hipMemsetAsync(deg, 0, (size_t)N_NODES * 2 * 4, stream);   // deg + cursor
    hipMemsetAsync(bnacc, 0, 2 * HC * 4, stream);

    // CSR build
    hist_kernel<<<(N_EDGES + 255) / 256, 256, 0, stream>>>(ei, deg);
    scanA_kernel<<<40, 1024, 0, stream>>>(deg, rowstart, blocksum);
    scanB_kernel<<<1, 64, 0, stream>>>(blocksum, blockoff);
    scanC_kernel<<<40, 1024, 0, stream>>>(rowstart, blockoff);
    scatter_kernel<<<(N_EDGES + 255) / 256, 256, 0, stream>>>(ei, rowstart, cursor, esorted);

    // converts
    cvt_f32_bf16_kernel<<<(N_NODES * F_IN / 4 + 255) / 256, 256, 0, stream>>>(
        x, x_b, N_NODES * F_IN / 4);
    wconv_kernel<<<(F_IN * HC + 255) / 256, 256, 0, stream>>>(W1, W1t, F_IN, HC);
    wconv_kernel<<<(HC * HC + 255) / 256, 256, 0, stream>>>(W2, W2t, HC, HC);
    wconv_kernel<<<(HC * NOUT + 255) / 256, 256, 0, stream>>>(linW, linWt, HC, NOUT);

    // ---- layer 1 ----
    mfma_gemm<0><<<dim3(N_NODES / 64, HC / 64), 256, 0, stream>>>(
        x_b, nullptr, nullptr, W1t, hpre_b, nullptr, nullptr, F_IN, HC);
    scores_kernel<<<N_NODES / 4, 256, 0, stream>>>(hpre_b, a1_src, a1_dst, e_src, e_dst);
    aggregate_kernel<<<N_NODES / 4, 256, 0, stream>>>(hpre_b, e_src, e_dst, rowstart,
                                                      esorted, b1, h1);
    bn_stats_kernel<<<N_NODES / 200, 256, 0, stream>>>(h1, bnacc);
    bn_finalize_kernel<<<1, 256, 0, stream>>>(bnacc, bn_g, bn_b, bnsc);
    bn_apply_elu_kernel<<<(N_NODES * HC / 4) / 256, 256, 0, stream>>>(h1, h1_b, bnsc);

    // ---- layer 2 ----
    mfma_gemm<0><<<dim3(N_NODES / 64, HC / 64), 256, 0, stream>>>(
        h1_b, nullptr, nullptr, W2t, hpre_b, nullptr, nullptr, HC, HC);
    scores_kernel<<<N_NODES / 4, 256, 0, stream>>>(hpre_b, a2_src, a2_dst, e_src, e_dst);
    aggregate_kernel<<<N_NODES / 4, 256, 0, stream>>>(hpre_b, e_src, e_dst, rowstart,
                                                      esorted, b2, h2);

    // ---- JK max + final linear ----
    mfma_gemm<1><<<dim3(N_NODES / 64, NOUT / 64), 256, 0, stream>>>(
        nullptr, h1, h2, linWt, nullptr, out, linb, HC, NOUT);
}

// Round 3
// 303.133 us; speedup vs baseline: 1.7409x; 1.0722x over previous
//
#include <hip/hip_runtime.h>
#include <math.h>

#define N_NODES 40000
#define N_EDGES 320000
#define F_IN 128
#define NHEAD 4
#define HC 256
#define NOUT 64

typedef __attribute__((ext_vector_type(8))) __bf16 bf16x8;
typedef __attribute__((ext_vector_type(4))) float f32x4;

static __device__ __forceinline__ unsigned short f2bf(float f) {
    union { float f; unsigned u; } v; v.f = f;
    unsigned r = v.u + 0x7FFFu + ((v.u >> 16) & 1u);
    return (unsigned short)(r >> 16);
}
static __device__ __forceinline__ float bf2f(unsigned short s) {
    union { unsigned u; float f; } v; v.u = ((unsigned)s) << 16;
    return v.f;
}

// ---------------- CSR build ----------------
__global__ __launch_bounds__(256) void hist_kernel(const int* __restrict__ ei,
                                                   int* __restrict__ deg) {
    int e = blockIdx.x * 256 + threadIdx.x;
    if (e < N_EDGES) atomicAdd(&deg[ei[N_EDGES + e]], 1);
}

__global__ __launch_bounds__(1024) void scanA_kernel(const int* __restrict__ deg,
                                                     int* __restrict__ rowstart,
                                                     int* __restrict__ blocksum) {
    __shared__ int sm[1024];
    int t = threadIdx.x;
    int i = blockIdx.x * 1024 + t;
    int v = (i < N_NODES) ? deg[i] : 0;
    sm[t] = v;
    __syncthreads();
    for (int off = 1; off < 1024; off <<= 1) {
        int x = (t >= off) ? sm[t - off] : 0;
        __syncthreads();
        sm[t] += x;
        __syncthreads();
    }
    if (i < N_NODES) rowstart[i] = sm[t] - v;
    if (t == 1023) blocksum[blockIdx.x] = sm[1023];
}

__global__ __launch_bounds__(64) void scanB_kernel(int* __restrict__ blocksum,
                                                   int* __restrict__ blockoff) {
    int t = threadIdx.x;
    int v = (t < 40) ? blocksum[t] : 0;
    int s = v;
#pragma unroll
    for (int off = 1; off < 64; off <<= 1) {
        int x = __shfl_up(s, off, 64);
        if (t >= off) s += x;
    }
    if (t < 40) blockoff[t] = s - v;
}

__global__ __launch_bounds__(1024) void scanC_kernel(int* __restrict__ rowstart,
                                                     const int* __restrict__ blockoff) {
    int i = blockIdx.x * 1024 + threadIdx.x;
    if (i < N_NODES) rowstart[i] += blockoff[blockIdx.x];
    if (i == 0) rowstart[N_NODES] = N_EDGES;
}

__global__ __launch_bounds__(256) void scatter_kernel(const int* __restrict__ ei,
                                                      const int* __restrict__ rowstart,
                                                      int* __restrict__ cursor,
                                                      int* __restrict__ esorted) {
    int e = blockIdx.x * 256 + threadIdx.x;
    if (e >= N_EDGES) return;
    int d = ei[N_EDGES + e];
    int s = ei[e];
    int pos = rowstart[d] + atomicAdd(&cursor[d], 1);
    esorted[pos] = s;
}

// W [K,N] f32 -> Wt [N,K] bf16
__global__ __launch_bounds__(256) void wconv_kernel(const float* __restrict__ W,
                                                    unsigned short* __restrict__ Wt,
                                                    int K, int Nc) {
    int t = blockIdx.x * 256 + threadIdx.x;
    if (t >= K * Nc) return;
    int k = t / Nc, n = t - k * Nc;
    Wt[(size_t)n * K + k] = f2bf(W[t]);
}

// ---------------- MFMA bf16 GEMM, 64x64 tile, 256 threads ----------------
// AMODE 0: A = bf16[M,K].  AMODE 1: A = f32[M,K] (convert in staging).
// AMODE 2: A = max(A1 bf16, A2 bf16) (JK fusion).
// SCORES 1: also emit es/ed (head = blockIdx.y); C stored bf16.
// SCORES 0: C stored f32 + bias.
template <int AMODE, int SCORES>
__global__ __launch_bounds__(256) void mfma_gemm(const void* __restrict__ Aptr,
                                                 const void* __restrict__ A2ptr,
                                                 const unsigned short* __restrict__ Bt,
                                                 unsigned short* __restrict__ Cb,
                                                 float* __restrict__ Cf,
                                                 const float* __restrict__ bias,
                                                 const float* __restrict__ asrc,
                                                 const float* __restrict__ adst,
                                                 float* __restrict__ es,
                                                 float* __restrict__ ed,
                                                 int K, int Nc) {
    __shared__ unsigned short As[64 * 32];
    __shared__ unsigned short Bs[64 * 32];
    int tid = threadIdx.x;
    int row0 = blockIdx.x * 64, col0 = blockIdx.y * 64;
    int wave = tid >> 6, lane = tid & 63;
    int wm = wave >> 1, wn = wave & 1;
    int quad = lane >> 4, l16 = lane & 15;
    f32x4 acc[2][2];
#pragma unroll
    for (int mi = 0; mi < 2; ++mi)
#pragma unroll
        for (int ni = 0; ni < 2; ++ni) acc[mi][ni] = (f32x4){0.f, 0.f, 0.f, 0.f};

    int srow = tid >> 2, schunk = (tid & 3) * 8;
    for (int kc = 0; kc < K; kc += 32) {
        if (AMODE == 0) {
            int4 av = *(const int4*)((const unsigned short*)Aptr +
                                     (size_t)(row0 + srow) * K + kc + schunk);
            *(int4*)(&As[srow * 32 + schunk]) = av;
        } else if (AMODE == 1) {
            const float* Af = (const float*)Aptr;
            size_t base = (size_t)(row0 + srow) * K + kc + schunk;
            float4 u1 = *(const float4*)(Af + base);
            float4 u2 = *(const float4*)(Af + base + 4);
            ushort4 o1, o2;
            o1.x = f2bf(u1.x); o1.y = f2bf(u1.y); o1.z = f2bf(u1.z); o1.w = f2bf(u1.w);
            o2.x = f2bf(u2.x); o2.y = f2bf(u2.y); o2.z = f2bf(u2.z); o2.w = f2bf(u2.w);
            *(ushort4*)(&As[srow * 32 + schunk]) = o1;
            *(ushort4*)(&As[srow * 32 + schunk + 4]) = o2;
        } else {
            size_t base = (size_t)(row0 + srow) * K + kc + schunk;
            union { int4 v; unsigned short u[8]; } a, b;
            a.v = *(const int4*)((const unsigned short*)Aptr + base);
            b.v = *(const int4*)((const unsigned short*)A2ptr + base);
            unsigned short o[8];
#pragma unroll
            for (int j = 0; j < 8; ++j)
                o[j] = f2bf(fmaxf(bf2f(a.u[j]), bf2f(b.u[j])));
#pragma unroll
            for (int j = 0; j < 8; ++j) As[srow * 32 + schunk + j] = o[j];
        }
        {
            int4 bv = *(const int4*)(Bt + (size_t)(col0 + srow) * K + kc + schunk);
            *(int4*)(&Bs[srow * 32 + schunk]) = bv;
        }
        __syncthreads();
        bf16x8 af[2], bfr[2];
#pragma unroll
        for (int mi = 0; mi < 2; ++mi)
            af[mi] = *(const bf16x8*)(&As[(wm * 32 + mi * 16 + l16) * 32 + quad * 8]);
#pragma unroll
        for (int ni = 0; ni < 2; ++ni)
            bfr[ni] = *(const bf16x8*)(&Bs[(wn * 32 + ni * 16 + l16) * 32 + quad * 8]);
#pragma unroll
        for (int mi = 0; mi < 2; ++mi)
#pragma unroll
            for (int ni = 0; ni < 2; ++ni)
                acc[mi][ni] = __builtin_amdgcn_mfma_f32_16x16x32_bf16(
                    af[mi], bfr[ni], acc[mi][ni], 0, 0, 0);
        __syncthreads();
    }
    // ---- C store ----
#pragma unroll
    for (int mi = 0; mi < 2; ++mi)
#pragma unroll
        for (int ni = 0; ni < 2; ++ni) {
            int r0 = row0 + wm * 32 + mi * 16 + quad * 4;
            int c = col0 + wn * 32 + ni * 16 + l16;
#pragma unroll
            for (int r = 0; r < 4; ++r) {
                if (SCORES)
                    Cb[(size_t)(r0 + r) * Nc + c] = f2bf(acc[mi][ni][r]);
                else
                    Cf[(size_t)(r0 + r) * Nc + c] = acc[mi][ni][r] + bias[c];
            }
        }
    // ---- fused attention scores (head = blockIdx.y) ----
    if (SCORES) {
        int hh = blockIdx.y;
        float as_v[2], ad_v[2];
#pragma unroll
        for (int ni = 0; ni < 2; ++ni) {
            int cl = wn * 32 + ni * 16 + l16;
            as_v[ni] = asrc[hh * 64 + cl];
            ad_v[ni] = adst[hh * 64 + cl];
        }
        float ps[2][4], pd[2][4];
#pragma unroll
        for (int mi = 0; mi < 2; ++mi)
#pragma unroll
            for (int r = 0; r < 4; ++r) {
                float s = 0.f, d = 0.f;
#pragma unroll
                for (int ni = 0; ni < 2; ++ni) {
                    s += acc[mi][ni][r] * as_v[ni];
                    d += acc[mi][ni][r] * ad_v[ni];
                }
#pragma unroll
                for (int off = 1; off < 16; off <<= 1) {
                    s += __shfl_xor(s, off);
                    d += __shfl_xor(d, off);
                }
                ps[mi][r] = s; pd[mi][r] = d;
            }
        float* sred = (float*)As;  // k-loop ended with __syncthreads -> safe alias
        if (l16 == 0) {
#pragma unroll
            for (int mi = 0; mi < 2; ++mi)
#pragma unroll
                for (int r = 0; r < 4; ++r) {
                    int rl = wm * 32 + mi * 16 + quad * 4 + r;
                    sred[(rl) * 2 + wn] = ps[mi][r];
                    sred[128 + (rl) * 2 + wn] = pd[mi][r];
                }
        }
        __syncthreads();
        if (tid < 64) {
            float s = sred[tid * 2 + 0] + sred[tid * 2 + 1];
            float d = sred[128 + tid * 2 + 0] + sred[128 + tid * 2 + 1];
            es[(size_t)(row0 + tid) * NHEAD + hh] = s;
            ed[(size_t)(row0 + tid) * NHEAD + hh] = d;
        }
    }
}

// ---------------- single-pass softmax + aggregation, ILP-batched ----------
__global__ __launch_bounds__(256) void aggregate_kernel(const unsigned short* __restrict__ h,
                                                        const float* __restrict__ es,
                                                        const float* __restrict__ ed,
                                                        const int* __restrict__ rowstart,
                                                        const int* __restrict__ esorted,
                                                        const float* __restrict__ bias,
                                                        unsigned short* __restrict__ outb) {
    int node = blockIdx.x * 4 + (threadIdx.x >> 6);
    int lane = threadIdx.x & 63;
    int hh = lane >> 4;
    float edv = ed[node * NHEAD + hh];
    int beg = rowstart[node], end = rowstart[node + 1];
    float dsum = 0.f;
    float ax = 0.f, ay = 0.f, az = 0.f, aw = 0.f;
    int i = beg;
    for (; i + 8 <= end; i += 8) {
        int s[8];
        ushort4 hv[8];
        float ep[8];
#pragma unroll
        for (int j = 0; j < 8; ++j) s[j] = esorted[i + j];
#pragma unroll
        for (int j = 0; j < 8; ++j)
            hv[j] = *(const ushort4*)(h + (size_t)s[j] * HC + lane * 4);
#pragma unroll
        for (int j = 0; j < 8; ++j) ep[j] = es[s[j] * NHEAD + hh];
#pragma unroll
        for (int j = 0; j < 8; ++j) {
            float e = ep[j] + edv;
            e = e > 0.f ? e : 0.2f * e;
            float w = __expf(e);
            dsum += w;
            ax += w * bf2f(hv[j].x); ay += w * bf2f(hv[j].y);
            az += w * bf2f(hv[j].z); aw += w * bf2f(hv[j].w);
        }
    }
    for (; i + 4 <= end; i += 4) {
        int s[4];
        ushort4 hv[4];
        float ep[4];
#pragma unroll
        for (int j = 0; j < 4; ++j) s[j] = esorted[i + j];
#pragma unroll
        for (int j = 0; j < 4; ++j)
            hv[j] = *(const ushort4*)(h + (size_t)s[j] * HC + lane * 4);
#pragma unroll
        for (int j = 0; j < 4; ++j) ep[j] = es[s[j] * NHEAD + hh];
#pragma unroll
        for (int j = 0; j < 4; ++j) {
            float e = ep[j] + edv;
            e = e > 0.f ? e : 0.2f * e;
            float w = __expf(e);
            dsum += w;
            ax += w * bf2f(hv[j].x); ay += w * bf2f(hv[j].y);
            az += w * bf2f(hv[j].z); aw += w * bf2f(hv[j].w);
        }
    }
    for (; i < end; ++i) {
        int s = esorted[i];
        ushort4 hv = *(const ushort4*)(h + (size_t)s * HC + lane * 4);
        float e = es[s * NHEAD + hh] + edv;
        e = e > 0.f ? e : 0.2f * e;
        float w = __expf(e);
        dsum += w;
        ax += w * bf2f(hv.x); ay += w * bf2f(hv.y);
        az += w * bf2f(hv.z); aw += w * bf2f(hv.w);
    }
    float inv = 1.f / (dsum + 1e-16f);
    float4 bv = *(const float4*)(bias + lane * 4);
    ushort4 o;
    o.x = f2bf(ax * inv + bv.x);
    o.y = f2bf(ay * inv + bv.y);
    o.z = f2bf(az * inv + bv.z);
    o.w = f2bf(aw * inv + bv.w);
    *(ushort4*)(outb + (size_t)node * HC + lane * 4) = o;
}

// ---------------- batch norm (bf16 in) ----------------
__global__ __launch_bounds__(256) void bn_stats_kernel(const unsigned short* __restrict__ x,
                                                       float* __restrict__ acc) {
    int c = threadIdx.x;
    int r0 = blockIdx.x * 200;
    float s = 0.f, s2 = 0.f;
    for (int r = r0; r < r0 + 200; ++r) {
        float v = bf2f(x[(size_t)r * HC + c]);
        s += v; s2 += v * v;
    }
    atomicAdd(&acc[c], s);
    atomicAdd(&acc[HC + c], s2);
}

__global__ __launch_bounds__(256) void bn_finalize_kernel(const float* __restrict__ acc,
                                                          const float* __restrict__ gamma,
                                                          const float* __restrict__ beta,
                                                          float* __restrict__ sc) {
    int c = threadIdx.x;
    float mean = acc[c] * (1.f / N_NODES);
    float var = acc[HC + c] * (1.f / N_NODES) - mean * mean;
    float inv = rsqrtf(var + 1e-5f);
    float scale = gamma[c] * inv;
    sc[c] = scale;
    sc[HC + c] = beta[c] - mean * scale;
}

// y = bf16(elu(x*scale+shift)), 8 elems/thread
__global__ __launch_bounds__(256) void bn_apply_elu_kernel(const unsigned short* __restrict__ xin,
                                                           unsigned short* __restrict__ xout,
                                                           const float* __restrict__ sc) {
    int idx = blockIdx.x * 256 + threadIdx.x;
    size_t off = (size_t)idx * 8;
    int c = (int)(off & (HC - 1));
    union { int4 v; unsigned short u[8]; } a;
    a.v = *(const int4*)(xin + off);
    unsigned short o[8];
#pragma unroll
    for (int j = 0; j < 8; ++j) {
        float v = bf2f(a.u[j]) * sc[c + j] + sc[HC + c + j];
        v = v > 0.f ? v : expm1f(v);
        o[j] = f2bf(v);
    }
    union { int4 v; unsigned short u[8]; } ov;
#pragma unroll
    for (int j = 0; j < 8; ++j) ov.u[j] = o[j];
    *(int4*)(xout + off) = ov.v;
}

extern "C" void kernel_launch(void* const* d_in, const int* in_sizes, int n_in,
                              void* d_out, int out_size, void* d_ws, size_t ws_size,
                              hipStream_t stream) {
    const float* x      = (const float*)d_in[0];
    const int*   ei     = (const int*)d_in[1];
    const float* W1     = (const float*)d_in[2];
    const float* a1_src = (const float*)d_in[3];
    const float* a1_dst = (const float*)d_in[4];
    const float* b1     = (const float*)d_in[5];
    const float* bn_g   = (const float*)d_in[6];
    const float* bn_b   = (const float*)d_in[7];
    const float* W2     = (const float*)d_in[8];
    const float* a2_src = (const float*)d_in[9];
    const float* a2_dst = (const float*)d_in[10];
    const float* b2     = (const float*)d_in[11];
    const float* linW   = (const float*)d_in[12];
    const float* linb   = (const float*)d_in[13];
    float* out = (float*)d_out;

    char* ws = (char*)d_ws;
    const size_t NHC_BF = (size_t)N_NODES * HC * 2;   // 20.48 MB
    unsigned short* hpre_b  = (unsigned short*)(ws);
    unsigned short* h1agg_b = (unsigned short*)(ws + NHC_BF);
    unsigned short* h1_b    = (unsigned short*)(ws + 2 * NHC_BF);
    unsigned short* h2_b    = (unsigned short*)(ws + 3 * NHC_BF);
    char* p = ws + 4 * NHC_BF;
    unsigned short* W1t   = (unsigned short*)p; p += (size_t)F_IN * HC * 2;
    unsigned short* W2t   = (unsigned short*)p; p += (size_t)HC * HC * 2;
    unsigned short* linWt = (unsigned short*)p; p += (size_t)HC * NOUT * 2;
    float* e_src   = (float*)p;  p += (size_t)N_NODES * NHEAD * 4;
    float* e_dst   = (float*)p;  p += (size_t)N_NODES * NHEAD * 4;
    int*   deg     = (int*)p;    p += (size_t)N_NODES * 4;
    int*   cursor  = (int*)p;    p += (size_t)N_NODES * 4;
    int*   rowstart= (int*)p;    p += ((size_t)N_NODES + 64) * 4;
    int*   esorted = (int*)p;    p += (size_t)N_EDGES * 4;
    int*   blocksum= (int*)p;    p += 64 * 4;
    int*   blockoff= (int*)p;    p += 64 * 4;
    float* bnacc   = (float*)p;  p += 2 * HC * 4;
    float* bnsc    = (float*)p;  p += 2 * HC * 4;

    hipMemsetAsync(deg, 0, (size_t)N_NODES * 2 * 4, stream);   // deg + cursor
    hipMemsetAsync(bnacc, 0, 2 * HC * 4, stream);

    // CSR build
    hist_kernel<<<(N_EDGES + 255) / 256, 256, 0, stream>>>(ei, deg);
    scanA_kernel<<<40, 1024, 0, stream>>>(deg, rowstart, blocksum);
    scanB_kernel<<<1, 64, 0, stream>>>(blocksum, blockoff);
    scanC_kernel<<<40, 1024, 0, stream>>>(rowstart, blockoff);
    scatter_kernel<<<(N_EDGES + 255) / 256, 256, 0, stream>>>(ei, rowstart, cursor, esorted);

    // weight converts
    wconv_kernel<<<(F_IN * HC + 255) / 256, 256, 0, stream>>>(W1, W1t, F_IN, HC);
    wconv_kernel<<<(HC * HC + 255) / 256, 256, 0, stream>>>(W2, W2t, HC, HC);
    wconv_kernel<<<(HC * NOUT + 255) / 256, 256, 0, stream>>>(linW, linWt, HC, NOUT);

    // ---- layer 1: GEMM (f32 A converted in staging) + fused scores ----
    mfma_gemm<1, 1><<<dim3(N_NODES / 64, HC / 64), 256, 0, stream>>>(
        x, nullptr, W1t, hpre_b, nullptr, nullptr, a1_src, a1_dst,
        e_src, e_dst, F_IN, HC);
    aggregate_kernel<<<N_NODES / 4, 256, 0, stream>>>(hpre_b, e_src, e_dst, rowstart,
                                                      esorted, b1, h1agg_b);
    bn_stats_kernel<<<N_NODES / 200, 256, 0, stream>>>(h1agg_b, bnacc);
    bn_finalize_kernel<<<1, 256, 0, stream>>>(bnacc, bn_g, bn_b, bnsc);
    bn_apply_elu_kernel<<<(N_NODES * HC / 8) / 256, 256, 0, stream>>>(h1agg_b, h1_b, bnsc);

    // ---- layer 2 ----
    mfma_gemm<0, 1><<<dim3(N_NODES / 64, HC / 64), 256, 0, stream>>>(
        h1_b, nullptr, W2t, hpre_b, nullptr, nullptr, a2_src, a2_dst,
        e_src, e_dst, HC, HC);
    aggregate_kernel<<<N_NODES / 4, 256, 0, stream>>>(hpre_b, e_src, e_dst, rowstart,
                                                      esorted, b2, h2_b);

    // ---- JK max (fused) + final linear ----
    mfma_gemm<2, 0><<<dim3(N_NODES / 64, NOUT / 64), 256, 0, stream>>>(
        h1_b, h2_b, linWt, nullptr, out, linb, nullptr, nullptr,
        nullptr, nullptr, HC, NOUT);
}

// Round 4
// 271.610 us; speedup vs baseline: 1.9430x; 1.1161x over previous
//
#include <hip/hip_runtime.h>
#include <math.h>

#define N_NODES 40000
#define N_EDGES 320000
#define F_IN 128
#define NHEAD 4
#define HC 256
#define NOUT 64

typedef __attribute__((ext_vector_type(8))) __bf16 bf16x8;
typedef __attribute__((ext_vector_type(4))) float f32x4;

static __device__ __forceinline__ unsigned short f2bf(float f) {
    union { float f; unsigned u; } v; v.f = f;
    unsigned r = v.u + 0x7FFFu + ((v.u >> 16) & 1u);
    return (unsigned short)(r >> 16);
}
static __device__ __forceinline__ float bf2f(unsigned short s) {
    union { unsigned u; float f; } v; v.u = ((unsigned)s) << 16;
    return v.f;
}

// ---------------- prep: weight converts + zeroing (one kernel) ------------
// blocks [0,128): W1 [128,256] -> W1t [256,128]
// blocks [128,384): W2 [256,256] -> W2t [256,256]
// blocks [384,448): linW [256,64] -> linWt [64,256]
// blocks [448,527): zero deg+cursor (80000 ints)
// block 527: zero bnacc (512 floats)
__global__ __launch_bounds__(256) void prep_kernel(const float* __restrict__ W1,
                                                   const float* __restrict__ W2,
                                                   const float* __restrict__ linW,
                                                   unsigned short* __restrict__ W1t,
                                                   unsigned short* __restrict__ W2t,
                                                   unsigned short* __restrict__ linWt,
                                                   int* __restrict__ zero_ints,
                                                   float* __restrict__ bnacc) {
    int b = blockIdx.x, tid = threadIdx.x;
    if (b < 128) {
        int t = b * 256 + tid;            // K=128, Nc=256
        int k = t >> 8, n = t & 255;
        W1t[n * 128 + k] = f2bf(W1[t]);
    } else if (b < 384) {
        int t = (b - 128) * 256 + tid;    // K=256, Nc=256
        int k = t >> 8, n = t & 255;
        W2t[n * 256 + k] = f2bf(W2[t]);
    } else if (b < 448) {
        int t = (b - 384) * 256 + tid;    // K=256, Nc=64
        int k = t >> 6, n = t & 63;
        linWt[n * 256 + k] = f2bf(linW[t]);
    } else if (b < 527) {
        int i = (b - 448) * 1024 + tid * 4;
        if (i < 80000) *(int4*)(zero_ints + i) = make_int4(0, 0, 0, 0);
    } else {
        if (tid < 512) bnacc[tid] = 0.f;
    }
}

// ---------------- CSR build ----------------
__global__ __launch_bounds__(256) void hist_kernel(const int* __restrict__ ei,
                                                   int* __restrict__ deg) {
    int e = blockIdx.x * 256 + threadIdx.x;
    if (e < N_EDGES) atomicAdd(&deg[ei[N_EDGES + e]], 1);
}

__global__ __launch_bounds__(1024) void scanA_kernel(const int* __restrict__ deg,
                                                     int* __restrict__ rowstart,
                                                     int* __restrict__ blocksum) {
    __shared__ int sm[1024];
    int t = threadIdx.x;
    int i = blockIdx.x * 1024 + t;
    int v = (i < N_NODES) ? deg[i] : 0;
    sm[t] = v;
    __syncthreads();
    for (int off = 1; off < 1024; off <<= 1) {
        int x = (t >= off) ? sm[t - off] : 0;
        __syncthreads();
        sm[t] += x;
        __syncthreads();
    }
    if (i < N_NODES) rowstart[i] = sm[t] - v;
    if (t == 1023) blocksum[blockIdx.x] = sm[1023];
}

__global__ __launch_bounds__(64) void scanB_kernel(int* __restrict__ blocksum,
                                                   int* __restrict__ blockoff) {
    int t = threadIdx.x;
    int v = (t < 40) ? blocksum[t] : 0;
    int s = v;
#pragma unroll
    for (int off = 1; off < 64; off <<= 1) {
        int x = __shfl_up(s, off, 64);
        if (t >= off) s += x;
    }
    if (t < 40) blockoff[t] = s - v;
}

__global__ __launch_bounds__(1024) void scanC_kernel(int* __restrict__ rowstart,
                                                     const int* __restrict__ blockoff) {
    int i = blockIdx.x * 1024 + threadIdx.x;
    if (i < N_NODES) rowstart[i] += blockoff[blockIdx.x];
    if (i == 0) rowstart[N_NODES] = N_EDGES;
}

__global__ __launch_bounds__(256) void scatter_kernel(const int* __restrict__ ei,
                                                      const int* __restrict__ rowstart,
                                                      int* __restrict__ cursor,
                                                      int* __restrict__ esorted) {
    int e = blockIdx.x * 256 + threadIdx.x;
    if (e >= N_EDGES) return;
    int d = ei[N_EDGES + e];
    int s = ei[e];
    int pos = rowstart[d] + atomicAdd(&cursor[d], 1);
    esorted[pos] = s;
}

// ---------------- wide MFMA GEMM: 64 rows x 256 cols per block -------------
// 4 waves; wave w computes cols [w*64, w*64+64) == head w. Fused scores.
// AMODE 1: A = f32[M,K] (convert in staging)
// AMODE 3: A = bf16[M,K], apply elu(x*sc[c]+sc[HC+c]) in staging (c = k index)
template <int AMODE>
__global__ __launch_bounds__(256) void gemm_wide(const void* __restrict__ Aptr,
                                                 const unsigned short* __restrict__ Bt,
                                                 const float* __restrict__ sc,
                                                 unsigned short* __restrict__ Cb,
                                                 const float* __restrict__ asrc,
                                                 const float* __restrict__ adst,
                                                 float* __restrict__ es,
                                                 float* __restrict__ ed,
                                                 int K) {
    __shared__ unsigned short As[64 * 32];
    __shared__ unsigned short Bs[256 * 32];
    int tid = threadIdx.x;
    int row0 = blockIdx.x * 64;
    int w = tid >> 6, lane = tid & 63;
    int quad = lane >> 4, l16 = lane & 15;
    f32x4 acc[4][4];
#pragma unroll
    for (int mi = 0; mi < 4; ++mi)
#pragma unroll
        for (int ni = 0; ni < 4; ++ni) acc[mi][ni] = (f32x4){0.f, 0.f, 0.f, 0.f};

    int srow = tid >> 2, schunk = (tid & 3) * 8;
    int brow = tid >> 1, bchunk = (tid & 1) * 16;
    for (int kc = 0; kc < K; kc += 32) {
        if (AMODE == 1) {
            const float* Af = (const float*)Aptr;
            size_t base = (size_t)(row0 + srow) * K + kc + schunk;
            float4 u1 = *(const float4*)(Af + base);
            float4 u2 = *(const float4*)(Af + base + 4);
            ushort4 o1, o2;
            o1.x = f2bf(u1.x); o1.y = f2bf(u1.y); o1.z = f2bf(u1.z); o1.w = f2bf(u1.w);
            o2.x = f2bf(u2.x); o2.y = f2bf(u2.y); o2.z = f2bf(u2.z); o2.w = f2bf(u2.w);
            *(ushort4*)(&As[srow * 32 + schunk]) = o1;
            *(ushort4*)(&As[srow * 32 + schunk + 4]) = o2;
        } else {
            size_t base = (size_t)(row0 + srow) * K + kc + schunk;
            union { int4 v; unsigned short u[8]; } a;
            a.v = *(const int4*)((const unsigned short*)Aptr + base);
            union { int4 v; unsigned short u[8]; } o;
#pragma unroll
            for (int j = 0; j < 8; ++j) {
                int c = kc + schunk + j;
                float v = bf2f(a.u[j]) * sc[c] + sc[HC + c];
                v = v > 0.f ? v : expm1f(v);
                o.u[j] = f2bf(v);
            }
            *(int4*)(&As[srow * 32 + schunk]) = o.v;
        }
#pragma unroll
        for (int p = 0; p < 2; ++p) {
            int n = p * 128 + brow;
            const unsigned short* src = Bt + (size_t)n * K + kc + bchunk;
            *(int4*)(&Bs[n * 32 + bchunk]) = *(const int4*)src;
            *(int4*)(&Bs[n * 32 + bchunk + 8]) = *(const int4*)(src + 8);
        }
        __syncthreads();
        bf16x8 af[4], bfr[4];
#pragma unroll
        for (int mi = 0; mi < 4; ++mi)
            af[mi] = *(const bf16x8*)(&As[(mi * 16 + l16) * 32 + quad * 8]);
#pragma unroll
        for (int ni = 0; ni < 4; ++ni)
            bfr[ni] = *(const bf16x8*)(&Bs[(w * 64 + ni * 16 + l16) * 32 + quad * 8]);
#pragma unroll
        for (int mi = 0; mi < 4; ++mi)
#pragma unroll
            for (int ni = 0; ni < 4; ++ni)
                acc[mi][ni] = __builtin_amdgcn_mfma_f32_16x16x32_bf16(
                    af[mi], bfr[ni], acc[mi][ni], 0, 0, 0);
        __syncthreads();
    }
    // C store (bf16)
#pragma unroll
    for (int mi = 0; mi < 4; ++mi)
#pragma unroll
        for (int ni = 0; ni < 4; ++ni) {
            int r0 = row0 + mi * 16 + quad * 4;
            int c = w * 64 + ni * 16 + l16;
#pragma unroll
            for (int r = 0; r < 4; ++r)
                Cb[(size_t)(r0 + r) * HC + c] = f2bf(acc[mi][ni][r]);
        }
    // fused attention scores: head = w, fully wave-local
    float as_v[4], ad_v[4];
#pragma unroll
    for (int ni = 0; ni < 4; ++ni) {
        int cl = ni * 16 + l16;
        as_v[ni] = asrc[w * 64 + cl];
        ad_v[ni] = adst[w * 64 + cl];
    }
#pragma unroll
    for (int mi = 0; mi < 4; ++mi)
#pragma unroll
        for (int r = 0; r < 4; ++r) {
            float s = 0.f, d = 0.f;
#pragma unroll
            for (int ni = 0; ni < 4; ++ni) {
                s += acc[mi][ni][r] * as_v[ni];
                d += acc[mi][ni][r] * ad_v[ni];
            }
#pragma unroll
            for (int off = 1; off < 16; off <<= 1) {
                s += __shfl_xor(s, off);
                d += __shfl_xor(d, off);
            }
            if (l16 == 0) {
                int row = row0 + mi * 16 + quad * 4 + r;
                es[(size_t)row * NHEAD + w] = s;
                ed[(size_t)row * NHEAD + w] = d;
            }
        }
}

// ---------------- final GEMM: out = max(elu(bn(h1agg)), h2) @ linWt + b ----
__global__ __launch_bounds__(256) void final_gemm(const unsigned short* __restrict__ A1,
                                                  const unsigned short* __restrict__ A2,
                                                  const unsigned short* __restrict__ Bt,
                                                  const float* __restrict__ sc,
                                                  const float* __restrict__ bias,
                                                  float* __restrict__ Cf) {
    __shared__ unsigned short As[64 * 32];
    __shared__ unsigned short Bs[64 * 32];
    int tid = threadIdx.x;
    int row0 = blockIdx.x * 64;
    int wave = tid >> 6, lane = tid & 63;
    int wm = wave >> 1, wn = wave & 1;
    int quad = lane >> 4, l16 = lane & 15;
    f32x4 acc[2][2];
#pragma unroll
    for (int mi = 0; mi < 2; ++mi)
#pragma unroll
        for (int ni = 0; ni < 2; ++ni) acc[mi][ni] = (f32x4){0.f, 0.f, 0.f, 0.f};

    int srow = tid >> 2, schunk = (tid & 3) * 8;
    for (int kc = 0; kc < HC; kc += 32) {
        {
            size_t base = (size_t)(row0 + srow) * HC + kc + schunk;
            union { int4 v; unsigned short u[8]; } a, b;
            a.v = *(const int4*)(A1 + base);
            b.v = *(const int4*)(A2 + base);
            union { int4 v; unsigned short u[8]; } o;
#pragma unroll
            for (int j = 0; j < 8; ++j) {
                int c = kc + schunk + j;
                float v1 = bf2f(a.u[j]) * sc[c] + sc[HC + c];
                v1 = v1 > 0.f ? v1 : expm1f(v1);
                o.u[j] = f2bf(fmaxf(v1, bf2f(b.u[j])));
            }
            *(int4*)(&As[srow * 32 + schunk]) = o.v;
        }
        {
            int4 bv = *(const int4*)(Bt + (size_t)srow * HC + kc + schunk);
            *(int4*)(&Bs[srow * 32 + schunk]) = bv;
        }
        __syncthreads();
        bf16x8 af[2], bfr[2];
#pragma unroll
        for (int mi = 0; mi < 2; ++mi)
            af[mi] = *(const bf16x8*)(&As[(wm * 32 + mi * 16 + l16) * 32 + quad * 8]);
#pragma unroll
        for (int ni = 0; ni < 2; ++ni)
            bfr[ni] = *(const bf16x8*)(&Bs[(wn * 32 + ni * 16 + l16) * 32 + quad * 8]);
#pragma unroll
        for (int mi = 0; mi < 2; ++mi)
#pragma unroll
            for (int ni = 0; ni < 2; ++ni)
                acc[mi][ni] = __builtin_amdgcn_mfma_f32_16x16x32_bf16(
                    af[mi], bfr[ni], acc[mi][ni], 0, 0, 0);
        __syncthreads();
    }
#pragma unroll
    for (int mi = 0; mi < 2; ++mi)
#pragma unroll
        for (int ni = 0; ni < 2; ++ni) {
            int r0 = row0 + wm * 32 + mi * 16 + quad * 4;
            int c = wn * 32 + ni * 16 + l16;
#pragma unroll
            for (int r = 0; r < 4; ++r)
                Cf[(size_t)(r0 + r) * NOUT + c] = acc[mi][ni][r] + bias[c];
        }
}

// ---------------- single-pass softmax + aggregation, ILP-batched ----------
__global__ __launch_bounds__(256) void aggregate_kernel(const unsigned short* __restrict__ h,
                                                        const float* __restrict__ es,
                                                        const float* __restrict__ ed,
                                                        const int* __restrict__ rowstart,
                                                        const int* __restrict__ esorted,
                                                        const float* __restrict__ bias,
                                                        unsigned short* __restrict__ outb) {
    int node = blockIdx.x * 4 + (threadIdx.x >> 6);
    int lane = threadIdx.x & 63;
    int hh = lane >> 4;
    float edv = ed[node * NHEAD + hh];
    int beg = rowstart[node], end = rowstart[node + 1];
    float dsum = 0.f;
    float ax = 0.f, ay = 0.f, az = 0.f, aw = 0.f;
    int i = beg;
    for (; i + 8 <= end; i += 8) {
        int s[8];
        ushort4 hv[8];
        float ep[8];
#pragma unroll
        for (int j = 0; j < 8; ++j) s[j] = esorted[i + j];
#pragma unroll
        for (int j = 0; j < 8; ++j)
            hv[j] = *(const ushort4*)(h + (size_t)s[j] * HC + lane * 4);
#pragma unroll
        for (int j = 0; j < 8; ++j) ep[j] = es[s[j] * NHEAD + hh];
#pragma unroll
        for (int j = 0; j < 8; ++j) {
            float e = ep[j] + edv;
            e = e > 0.f ? e : 0.2f * e;
            float w = __expf(e);
            dsum += w;
            ax += w * bf2f(hv[j].x); ay += w * bf2f(hv[j].y);
            az += w * bf2f(hv[j].z); aw += w * bf2f(hv[j].w);
        }
    }
    for (; i + 4 <= end; i += 4) {
        int s[4];
        ushort4 hv[4];
        float ep[4];
#pragma unroll
        for (int j = 0; j < 4; ++j) s[j] = esorted[i + j];
#pragma unroll
        for (int j = 0; j < 4; ++j)
            hv[j] = *(const ushort4*)(h + (size_t)s[j] * HC + lane * 4);
#pragma unroll
        for (int j = 0; j < 4; ++j) ep[j] = es[s[j] * NHEAD + hh];
#pragma unroll
        for (int j = 0; j < 4; ++j) {
            float e = ep[j] + edv;
            e = e > 0.f ? e : 0.2f * e;
            float w = __expf(e);
            dsum += w;
            ax += w * bf2f(hv[j].x); ay += w * bf2f(hv[j].y);
            az += w * bf2f(hv[j].z); aw += w * bf2f(hv[j].w);
        }
    }
    for (; i < end; ++i) {
        int s = esorted[i];
        ushort4 hv = *(const ushort4*)(h + (size_t)s * HC + lane * 4);
        float e = es[s * NHEAD + hh] + edv;
        e = e > 0.f ? e : 0.2f * e;
        float w = __expf(e);
        dsum += w;
        ax += w * bf2f(hv.x); ay += w * bf2f(hv.y);
        az += w * bf2f(hv.z); aw += w * bf2f(hv.w);
    }
    float inv = 1.f / (dsum + 1e-16f);
    float4 bv = *(const float4*)(bias + lane * 4);
    ushort4 o;
    o.x = f2bf(ax * inv + bv.x);
    o.y = f2bf(ay * inv + bv.y);
    o.z = f2bf(az * inv + bv.z);
    o.w = f2bf(aw * inv + bv.w);
    *(ushort4*)(outb + (size_t)node * HC + lane * 4) = o;
}

// ---------------- batch norm stats + finalize ----------------
__global__ __launch_bounds__(256) void bn_stats_kernel(const unsigned short* __restrict__ x,
                                                       float* __restrict__ acc) {
    int c = threadIdx.x;
    int r0 = blockIdx.x * 200;
    float s = 0.f, s2 = 0.f;
    for (int r = r0; r < r0 + 200; ++r) {
        float v = bf2f(x[(size_t)r * HC + c]);
        s += v; s2 += v * v;
    }
    atomicAdd(&acc[c], s);
    atomicAdd(&acc[HC + c], s2);
}

__global__ __launch_bounds__(256) void bn_finalize_kernel(const float* __restrict__ acc,
                                                          const float* __restrict__ gamma,
                                                          const float* __restrict__ beta,
                                                          float* __restrict__ sc) {
    int c = threadIdx.x;
    float mean = acc[c] * (1.f / N_NODES);
    float var = acc[HC + c] * (1.f / N_NODES) - mean * mean;
    float inv = rsqrtf(var + 1e-5f);
    float scale = gamma[c] * inv;
    sc[c] = scale;
    sc[HC + c] = beta[c] - mean * scale;
}

extern "C" void kernel_launch(void* const* d_in, const int* in_sizes, int n_in,
                              void* d_out, int out_size, void* d_ws, size_t ws_size,
                              hipStream_t stream) {
    const float* x      = (const float*)d_in[0];
    const int*   ei     = (const int*)d_in[1];
    const float* W1     = (const float*)d_in[2];
    const float* a1_src = (const float*)d_in[3];
    const float* a1_dst = (const float*)d_in[4];
    const float* b1     = (const float*)d_in[5];
    const float* bn_g   = (const float*)d_in[6];
    const float* bn_b   = (const float*)d_in[7];
    const float* W2     = (const float*)d_in[8];
    const float* a2_src = (const float*)d_in[9];
    const float* a2_dst = (const float*)d_in[10];
    const float* b2     = (const float*)d_in[11];
    const float* linW   = (const float*)d_in[12];
    const float* linb   = (const float*)d_in[13];
    float* out = (float*)d_out;

    char* ws = (char*)d_ws;
    const size_t NHC_BF = (size_t)N_NODES * HC * 2;   // 20.48 MB
    unsigned short* hpre_b  = (unsigned short*)(ws);
    unsigned short* h1agg_b = (unsigned short*)(ws + NHC_BF);
    unsigned short* h2_b    = (unsigned short*)(ws + 2 * NHC_BF);
    char* p = ws + 3 * NHC_BF;
    unsigned short* W1t   = (unsigned short*)p; p += (size_t)F_IN * HC * 2;
    unsigned short* W2t   = (unsigned short*)p; p += (size_t)HC * HC * 2;
    unsigned short* linWt = (unsigned short*)p; p += (size_t)HC * NOUT * 2;
    float* e_src   = (float*)p;  p += (size_t)N_NODES * NHEAD * 4;
    float* e_dst   = (float*)p;  p += (size_t)N_NODES * NHEAD * 4;
    int*   deg     = (int*)p;    p += (size_t)N_NODES * 4;
    int*   cursor  = (int*)p;    p += (size_t)N_NODES * 4;
    int*   rowstart= (int*)p;    p += ((size_t)N_NODES + 64) * 4;
    int*   esorted = (int*)p;    p += (size_t)N_EDGES * 4;
    int*   blocksum= (int*)p;    p += 64 * 4;
    int*   blockoff= (int*)p;    p += 64 * 4;
    float* bnacc   = (float*)p;  p += 2 * HC * 4;
    float* bnsc    = (float*)p;  p += 2 * HC * 4;

    // prep: weight converts + zero deg/cursor/bnacc (replaces 3 kernels + 2 memsets)
    prep_kernel<<<528, 256, 0, stream>>>(W1, W2, linW, W1t, W2t, linWt, deg, bnacc);

    // CSR build
    hist_kernel<<<(N_EDGES + 255) / 256, 256, 0, stream>>>(ei, deg);
    scanA_kernel<<<40, 1024, 0, stream>>>(deg, rowstart, blocksum);
    scanB_kernel<<<1, 64, 0, stream>>>(blocksum, blockoff);
    scanC_kernel<<<40, 1024, 0, stream>>>(rowstart, blockoff);
    scatter_kernel<<<(N_EDGES + 255) / 256, 256, 0, stream>>>(ei, rowstart, cursor, esorted);

    // ---- layer 1: wide GEMM (f32 A) + fused scores ----
    gemm_wide<1><<<N_NODES / 64, 256, 0, stream>>>(
        x, W1t, nullptr, hpre_b, a1_src, a1_dst, e_src, e_dst, F_IN);
    aggregate_kernel<<<N_NODES / 4, 256, 0, stream>>>(hpre_b, e_src, e_dst, rowstart,
                                                      esorted, b1, h1agg_b);
    bn_stats_kernel<<<N_NODES / 200, 256, 0, stream>>>(h1agg_b, bnacc);
    bn_finalize_kernel<<<1, 256, 0, stream>>>(bnacc, bn_g, bn_b, bnsc);

    // ---- layer 2: wide GEMM with fused BN+ELU on A + fused scores ----
    gemm_wide<3><<<N_NODES / 64, 256, 0, stream>>>(
        h1agg_b, W2t, bnsc, hpre_b, a2_src, a2_dst, e_src, e_dst, HC);
    aggregate_kernel<<<N_NODES / 4, 256, 0, stream>>>(hpre_b, e_src, e_dst, rowstart,
                                                      esorted, b2, h2_b);

    // ---- final: JK max (BN+ELU on h1agg fused) + linear ----
    final_gemm<<<N_NODES / 64, 256, 0, stream>>>(h1agg_b, h2_b, linWt, bnsc, linb, out);
}